// Round 3
// baseline (59.812 us; speedup 1.0000x reference)
//
#include <hip/hip_runtime.h>

// LinearDecayMixup: out[row, :] = one_hot(label) if (rand < ratio && label >= 0)
//                                 else pred[row, :]
// B=64, N=1024, C=768 -> 65536 rows of 768 f32.
// One wave (64 lanes) per row, 3x float4 per lane (64*3*4 = 192 f4 = 768 f32).
// Mask is wave-uniform -> no divergence; masked rows skip the pred read.
// R2: nontemporal builtins require clang native vector type, not HIP float4.

#define C_CLS 768
#define F4_PER_ROW (C_CLS / 4)   // 192 float4 per row
#define F4_PER_LANE 3            // 64 lanes * 3 f4 = 192

typedef float fvec4 __attribute__((ext_vector_type(4)));

__global__ __launch_bounds__(256) void LinearDecayMixup_kernel(
    const float* __restrict__ pred,       // [rows, 768] f32
    const int*   __restrict__ labels,     // [rows] i32
    const float* __restrict__ rand_nums,  // [rows] f32
    const int*   __restrict__ cur_step_p, // [1]
    const int*   __restrict__ tot_step_p, // [1]
    float*       __restrict__ out,        // [rows, 768] f32
    int n_rows)
{
    // ---- schedule ratio (Python-float semantics, computed in double) ----
    const double cs = (double)cur_step_p[0];
    const double ts = (double)tot_step_p[0];
    double ratio;
    if (cs < ts * 0.2) {
        ratio = 1.0;
    } else if (cs < ts * 0.6) {
        ratio = (ts * 0.6 - cs) / (0.4 * ts);
    } else {
        ratio = 0.0;
    }

    const int lane       = threadIdx.x & 63;
    const int wavesPerBk = blockDim.x >> 6;
    const int totalWaves = gridDim.x * wavesPerBk;
    const int wave0      = blockIdx.x * wavesPerBk + (threadIdx.x >> 6);

    // Prefetch first row's mask operands
    int   label = (wave0 < n_rows) ? labels[wave0]    : -1;
    float rn    = (wave0 < n_rows) ? rand_nums[wave0] : 1.0f;

    for (int row = wave0; row < n_rows; row += totalWaves) {
        const bool mask = ((double)rn < ratio) && (label >= 0);
        const int  lc   = min(max(label, 0), C_CLS - 1);

        // Prefetch next iteration's mask operands (hide latency under stream)
        const int nrow = row + totalWaves;
        if (nrow < n_rows) {
            label = labels[nrow];
            rn    = rand_nums[nrow];
        }

        const fvec4* __restrict__ src = (const fvec4*)pred + (size_t)row * F4_PER_ROW;
        fvec4*       __restrict__ dst = (fvec4*)out        + (size_t)row * F4_PER_ROW;

        if (mask) {
            // one-hot row: no pred read needed
            #pragma unroll
            for (int i = 0; i < F4_PER_LANE; ++i) {
                const int f4   = lane + i * 64;       // coalesced across lanes
                const int base = f4 * 4;
                fvec4 v;
                v.x = (base + 0 == lc) ? 1.0f : 0.0f;
                v.y = (base + 1 == lc) ? 1.0f : 0.0f;
                v.z = (base + 2 == lc) ? 1.0f : 0.0f;
                v.w = (base + 3 == lc) ? 1.0f : 0.0f;
                __builtin_nontemporal_store(v, &dst[f4]);
            }
        } else {
            fvec4 v[F4_PER_LANE];
            #pragma unroll
            for (int i = 0; i < F4_PER_LANE; ++i) {
                const int f4 = lane + i * 64;         // coalesced across lanes
                v[i] = __builtin_nontemporal_load(&src[f4]);
            }
            #pragma unroll
            for (int i = 0; i < F4_PER_LANE; ++i) {
                const int f4 = lane + i * 64;
                __builtin_nontemporal_store(v[i], &dst[f4]);
            }
        }
    }
}

extern "C" void kernel_launch(void* const* d_in, const int* in_sizes, int n_in,
                              void* d_out, int out_size, void* d_ws, size_t ws_size,
                              hipStream_t stream) {
    const float* pred      = (const float*)d_in[0];
    const int*   labels    = (const int*)d_in[1];
    const float* rand_nums = (const float*)d_in[2];
    const int*   cur_step  = (const int*)d_in[3];
    const int*   tot_step  = (const int*)d_in[4];
    float*       out       = (float*)d_out;

    const int n_rows = in_sizes[1];  // B*N = 65536

    const int block = 256;                 // 4 waves/block
    const int wavesPerBlock = block / 64;
    int grid = (n_rows + wavesPerBlock - 1) / wavesPerBlock;
    if (grid > 2048) grid = 2048;          // grid-stride the rest

    LinearDecayMixup_kernel<<<grid, block, 0, stream>>>(
        pred, labels, rand_nums, cur_step, tot_step, out, n_rows);
}

// Round 4
// 54.465 us; speedup vs baseline: 1.0982x; 1.0982x over previous
//
#include <hip/hip_runtime.h>

// LinearDecayMixup: out[row, :] = one_hot(label) if (rand < ratio && label >= 0)
//                                 else pred[row, :]
// B=64, N=1024, C=768 -> 65536 rows of 768 f32.
// One wave (64 lanes) per row, 3x float4 per lane (64*3*4 = 192 f4 = 768 f32).
// Mask is wave-uniform -> no divergence; masked rows skip the pred read.
// R3: nontemporal REVERTED (measured -12%: nt bypasses L2 write combining).
//     Unroll grid-stride by 2 rows/iter, loads issued before stores (2x MLP).

#define C_CLS 768
#define F4_PER_ROW (C_CLS / 4)   // 192 float4 per row
#define F4_PER_LANE 3            // 64 lanes * 3 f4 = 192

typedef float fvec4 __attribute__((ext_vector_type(4)));

__device__ __forceinline__ void emit_row(fvec4* __restrict__ dst,
                                         const fvec4* __restrict__ src,
                                         bool mask, int lc, int lane)
{
    if (mask) {
        #pragma unroll
        for (int i = 0; i < F4_PER_LANE; ++i) {
            const int f4   = lane + i * 64;
            const int base = f4 * 4;
            fvec4 v;
            v.x = (base + 0 == lc) ? 1.0f : 0.0f;
            v.y = (base + 1 == lc) ? 1.0f : 0.0f;
            v.z = (base + 2 == lc) ? 1.0f : 0.0f;
            v.w = (base + 3 == lc) ? 1.0f : 0.0f;
            dst[f4] = v;
        }
    } else {
        fvec4 v[F4_PER_LANE];
        #pragma unroll
        for (int i = 0; i < F4_PER_LANE; ++i) v[i] = src[lane + i * 64];
        #pragma unroll
        for (int i = 0; i < F4_PER_LANE; ++i) dst[lane + i * 64] = v[i];
    }
}

__global__ __launch_bounds__(256) void LinearDecayMixup_kernel(
    const float* __restrict__ pred,       // [rows, 768] f32
    const int*   __restrict__ labels,     // [rows] i32
    const float* __restrict__ rand_nums,  // [rows] f32
    const int*   __restrict__ cur_step_p, // [1]
    const int*   __restrict__ tot_step_p, // [1]
    float*       __restrict__ out,        // [rows, 768] f32
    int n_rows)
{
    // ---- schedule ratio (Python-float semantics, computed in double) ----
    const double cs = (double)cur_step_p[0];
    const double ts = (double)tot_step_p[0];
    double ratio;
    if (cs < ts * 0.2) {
        ratio = 1.0;
    } else if (cs < ts * 0.6) {
        ratio = (ts * 0.6 - cs) / (0.4 * ts);
    } else {
        ratio = 0.0;
    }

    const int lane       = threadIdx.x & 63;
    const int wavesPerBk = blockDim.x >> 6;
    const int totalWaves = gridDim.x * wavesPerBk;
    const int wave0      = blockIdx.x * wavesPerBk + (threadIdx.x >> 6);

    // Process 2 rows per iteration: (row, row + totalWaves), step 2*totalWaves.
    for (int row = wave0; row < n_rows; row += 2 * totalWaves) {
        const int rowB  = row + totalWaves;
        const bool hasB = (rowB < n_rows);

        const int   labA = labels[row];
        const float rnA  = rand_nums[row];
        const int   labB = hasB ? labels[rowB]    : -1;
        const float rnB  = hasB ? rand_nums[rowB] : 1.0f;

        const bool maskA = ((double)rnA < ratio) && (labA >= 0);
        const bool maskB = ((double)rnB < ratio) && (labB >= 0);
        const int  lcA   = min(max(labA, 0), C_CLS - 1);
        const int  lcB   = min(max(labB, 0), C_CLS - 1);

        const fvec4* srcA = (const fvec4*)pred + (size_t)row  * F4_PER_ROW;
        fvec4*       dstA = (fvec4*)out        + (size_t)row  * F4_PER_ROW;
        const fvec4* srcB = (const fvec4*)pred + (size_t)rowB * F4_PER_ROW;
        fvec4*       dstB = (fvec4*)out        + (size_t)rowB * F4_PER_ROW;

        if (hasB && !maskA && !maskB) {
            // Both rows are copies: issue all 6 loads before any store (2x MLP)
            fvec4 vA[F4_PER_LANE], vB[F4_PER_LANE];
            #pragma unroll
            for (int i = 0; i < F4_PER_LANE; ++i) vA[i] = srcA[lane + i * 64];
            #pragma unroll
            for (int i = 0; i < F4_PER_LANE; ++i) vB[i] = srcB[lane + i * 64];
            #pragma unroll
            for (int i = 0; i < F4_PER_LANE; ++i) dstA[lane + i * 64] = vA[i];
            #pragma unroll
            for (int i = 0; i < F4_PER_LANE; ++i) dstB[lane + i * 64] = vB[i];
        } else {
            emit_row(dstA, srcA, maskA, lcA, lane);
            if (hasB) emit_row(dstB, srcB, maskB, lcB, lane);
        }
    }
}

extern "C" void kernel_launch(void* const* d_in, const int* in_sizes, int n_in,
                              void* d_out, int out_size, void* d_ws, size_t ws_size,
                              hipStream_t stream) {
    const float* pred      = (const float*)d_in[0];
    const int*   labels    = (const int*)d_in[1];
    const float* rand_nums = (const float*)d_in[2];
    const int*   cur_step  = (const int*)d_in[3];
    const int*   tot_step  = (const int*)d_in[4];
    float*       out       = (float*)d_out;

    const int n_rows = in_sizes[1];  // B*N = 65536

    const int block = 256;                 // 4 waves/block
    const int wavesPerBlock = block / 64;
    int grid = (n_rows + wavesPerBlock - 1) / wavesPerBlock;
    if (grid > 2048) grid = 2048;          // grid-stride the rest

    LinearDecayMixup_kernel<<<grid, block, 0, stream>>>(
        pred, labels, rand_nums, cur_step, tot_step, out, n_rows);
}

// Round 5
// 47.691 us; speedup vs baseline: 1.2541x; 1.1420x over previous
//
#include <hip/hip_runtime.h>

// LinearDecayMixup: out[row, :] = one_hot(label) if (rand < ratio && label >= 0)
//                                 else pred[row, :]
// B=64, N=1024, C=768 -> 65536 rows of 768 f32.
// One wave (64 lanes) per row, 3x float4 per lane (64*3*4 = 192 f4 = 768 f32).
// Mask is wave-uniform -> no divergence; masked rows skip the pred read.
// R3: nontemporal REVERTED (-12%). R4: 2-row unroll REVERTED (-2%).
// R4->R5: exact grid, one row per wave, no grid-stride loop (65536 waves).

#define C_CLS 768
#define F4_PER_ROW (C_CLS / 4)   // 192 float4 per row
#define F4_PER_LANE 3            // 64 lanes * 3 f4 = 192

typedef float fvec4 __attribute__((ext_vector_type(4)));

__global__ __launch_bounds__(256) void LinearDecayMixup_kernel(
    const float* __restrict__ pred,       // [rows, 768] f32
    const int*   __restrict__ labels,     // [rows] i32
    const float* __restrict__ rand_nums,  // [rows] f32
    const int*   __restrict__ cur_step_p, // [1]
    const int*   __restrict__ tot_step_p, // [1]
    float*       __restrict__ out,        // [rows, 768] f32
    int n_rows)
{
    // ---- schedule ratio (Python-float semantics, computed in double) ----
    const double cs = (double)cur_step_p[0];
    const double ts = (double)tot_step_p[0];
    double ratio;
    if (cs < ts * 0.2) {
        ratio = 1.0;
    } else if (cs < ts * 0.6) {
        ratio = (ts * 0.6 - cs) / (0.4 * ts);
    } else {
        ratio = 0.0;
    }

    const int lane = threadIdx.x & 63;
    const int row  = blockIdx.x * (blockDim.x >> 6) + (threadIdx.x >> 6);
    if (row >= n_rows) return;

    const int   label = labels[row];
    const float rn    = rand_nums[row];
    const bool  mask  = ((double)rn < ratio) && (label >= 0);

    const fvec4* __restrict__ src = (const fvec4*)pred + (size_t)row * F4_PER_ROW;
    fvec4*       __restrict__ dst = (fvec4*)out        + (size_t)row * F4_PER_ROW;

    if (mask) {
        // one-hot row: no pred read needed
        const int lc = min(max(label, 0), C_CLS - 1);
        #pragma unroll
        for (int i = 0; i < F4_PER_LANE; ++i) {
            const int f4   = lane + i * 64;       // coalesced across lanes
            const int base = f4 * 4;
            fvec4 v;
            v.x = (base + 0 == lc) ? 1.0f : 0.0f;
            v.y = (base + 1 == lc) ? 1.0f : 0.0f;
            v.z = (base + 2 == lc) ? 1.0f : 0.0f;
            v.w = (base + 3 == lc) ? 1.0f : 0.0f;
            dst[f4] = v;
        }
    } else {
        fvec4 v[F4_PER_LANE];
        #pragma unroll
        for (int i = 0; i < F4_PER_LANE; ++i) v[i] = src[lane + i * 64];
        #pragma unroll
        for (int i = 0; i < F4_PER_LANE; ++i) dst[lane + i * 64] = v[i];
    }
}

extern "C" void kernel_launch(void* const* d_in, const int* in_sizes, int n_in,
                              void* d_out, int out_size, void* d_ws, size_t ws_size,
                              hipStream_t stream) {
    const float* pred      = (const float*)d_in[0];
    const int*   labels    = (const int*)d_in[1];
    const float* rand_nums = (const float*)d_in[2];
    const int*   cur_step  = (const int*)d_in[3];
    const int*   tot_step  = (const int*)d_in[4];
    float*       out       = (float*)d_out;

    const int n_rows = in_sizes[1];  // B*N = 65536

    const int block = 256;                         // 4 waves/block
    const int wavesPerBlock = block / 64;
    const int grid = (n_rows + wavesPerBlock - 1) / wavesPerBlock;  // exact

    LinearDecayMixup_kernel<<<grid, block, 0, stream>>>(
        pred, labels, rand_nums, cur_step, tot_step, out, n_rows);
}